// Round 1
// baseline (21058.240 us; speedup 1.0000x reference)
//
#include <hip/hip_runtime.h>
#include <hip/hip_cooperative_groups.h>

namespace cg = cooperative_groups;

#define TSTEPS 512
#define BATCH  64
#define DIN    256
#define HID    512
#define G4H    2048
#define NWG    128
#define UPW    4            // hidden units per workgroup (NWG*UPW == HID)
#define NTHR   256
#define KTOT   768          // D + H
#define WST    776          // Wt LDS row stride in bf16 elems: 16B-aligned, <=2-way bank alias
#define GST    17           // gate staging stride (floats): 2-way bank alias max

typedef __attribute__((ext_vector_type(8))) short bf16x8;
typedef __attribute__((ext_vector_type(4))) float f32x4;

__device__ __forceinline__ unsigned short f2bf(float f) {
  unsigned u = __float_as_uint(f);
  u += 0x7fffu + ((u >> 16) & 1u);   // RNE truncate to bf16
  return (unsigned short)(u >> 16);
}
__device__ __forceinline__ float bf2f(unsigned short s) {
  return __uint_as_float((unsigned)s << 16);
}
__device__ __forceinline__ float sigm(float x) { return 1.0f / (1.0f + __expf(-x)); }

// One-time: split x (fp32) into hi/lo bf16 planes so the recurrent kernel's
// A-fragments are direct 16B loads with no per-step conversion VALU.
__global__ void split_x_kernel(const float* __restrict__ x,
                               unsigned short* __restrict__ xhi,
                               unsigned short* __restrict__ xlo, int n4) {
  int i = blockIdx.x * blockDim.x + threadIdx.x;
  if (i >= n4) return;
  float4 v = reinterpret_cast<const float4*>(x)[i];
  unsigned short h0 = f2bf(v.x), h1 = f2bf(v.y), h2 = f2bf(v.z), h3 = f2bf(v.w);
  ushort4 hi = make_ushort4(h0, h1, h2, h3);
  ushort4 lo = make_ushort4(f2bf(v.x - bf2f(h0)), f2bf(v.y - bf2f(h1)),
                            f2bf(v.z - bf2f(h2)), f2bf(v.w - bf2f(h3)));
  reinterpret_cast<ushort4*>(xhi)[i] = hi;
  reinterpret_cast<ushort4*>(xlo)[i] = lo;
}

// Persistent cooperative kernel: each WG owns UPW hidden units; W slice lives
// in LDS (hi/lo bf16, transposed [col][k]); h round-trips via double-buffered
// global hi/lo bf16; one grid.sync per timestep.
__global__ void __launch_bounds__(NTHR, 1)
lstm_persistent(const unsigned short* __restrict__ xhi,
                const unsigned short* __restrict__ xlo,
                const int* __restrict__ rst,
                const float* __restrict__ W,
                const float* __restrict__ bias,
                float* __restrict__ out,
                unsigned short* __restrict__ hbhi,
                unsigned short* __restrict__ hblo) {
  __shared__ unsigned short WtHi[16 * WST];
  __shared__ unsigned short WtLo[16 * WST];
  __shared__ float gateS[BATCH * GST];
  __shared__ float biasS[16];

  const int tid = threadIdx.x;
  const int wg  = blockIdx.x;
  const int j0  = wg * UPW;

  // --- prologue: W slice -> LDS (transposed, hi/lo), bias, zero h buffers ---
  for (int flat = tid; flat < KTOT * 16; flat += NTHR) {
    int k = flat >> 4;
    int c = flat & 15;                       // LDS col: sec*4 + u
    int gcol = (c >> 2) * HID + j0 + (c & 3); // i|g|f|o sections of 4H
    float w = W[(size_t)k * G4H + gcol];
    unsigned short h = f2bf(w);
    WtHi[c * WST + k] = h;
    WtLo[c * WST + k] = f2bf(w - bf2f(h));
  }
  if (tid < 16) biasS[tid] = bias[(tid >> 2) * HID + j0 + (tid & 3)];
  {
    int base = wg * 512 + tid * 2;           // 128 WGs x 512 = both h buffers
    hbhi[base] = 0; hbhi[base + 1] = 0;
    hblo[base] = 0; hblo[base + 1] = 0;
  }
  __syncthreads();
  cg::grid_group grid = cg::this_grid();
  grid.sync();

  // --- per-thread geometry ---
  const int lane = tid & 63;
  const int wave = tid >> 6;
  const int r0   = wave * 16;            // this wave's 16 batch rows
  const int arow = r0 + (lane & 15);     // A row (batch index)
  const int klo  = (lane >> 4) * 8;      // per-lane K base within K=32 chunk
  const int colA = lane & 15;            // output column within tile

  const unsigned short* bh_ = &WtHi[colA * WST + klo];
  const unsigned short* bl_ = &WtLo[colA * WST + klo];

  // activation-phase identity: one (batch, unit) pair per thread
  const int ab   = tid >> 2;             // batch 0..63
  const int au   = tid & 3;              // unit-in-group 0..3
  const int unit = j0 + au;
  float c_ = 0.0f;

  for (int t = 0; t < TSTEPS; ++t) {
    const int rb = (t & 1) * (BATCH * HID);
    const int wb = ((t + 1) & 1) * (BATCH * HID);
    f32x4 acc = {0.f, 0.f, 0.f, 0.f};
    const unsigned short* xrh = xhi + ((size_t)t * BATCH + arow) * DIN + klo;
    const unsigned short* xrl = xlo + ((size_t)t * BATCH + arow) * DIN + klo;
    const unsigned short* hrh = hbhi + rb + arow * HID + klo;
    const unsigned short* hrl = hblo + rb + arow * HID + klo;

    // K = 0..255 from x_t  (3-product bf16 split: ~fp32 accuracy)
#pragma unroll
    for (int kk = 0; kk < DIN / 32; ++kk) {
      int kb = kk * 32;
      bf16x8 ah = *reinterpret_cast<const bf16x8*>(xrh + kb);
      bf16x8 al = *reinterpret_cast<const bf16x8*>(xrl + kb);
      bf16x8 bh = *reinterpret_cast<const bf16x8*>(bh_ + kb);
      bf16x8 bl = *reinterpret_cast<const bf16x8*>(bl_ + kb);
      acc = __builtin_amdgcn_mfma_f32_16x16x32_bf16(ah, bh, acc, 0, 0, 0);
      acc = __builtin_amdgcn_mfma_f32_16x16x32_bf16(ah, bl, acc, 0, 0, 0);
      acc = __builtin_amdgcn_mfma_f32_16x16x32_bf16(al, bh, acc, 0, 0, 0);
    }
    // K = 256..767 from h (masked, previous step)
#pragma unroll
    for (int kk = 0; kk < HID / 32; ++kk) {
      int kb = kk * 32;
      bf16x8 ah = *reinterpret_cast<const bf16x8*>(hrh + kb);
      bf16x8 al = *reinterpret_cast<const bf16x8*>(hrl + kb);
      bf16x8 bh = *reinterpret_cast<const bf16x8*>(bh_ + DIN + kb);
      bf16x8 bl = *reinterpret_cast<const bf16x8*>(bl_ + DIN + kb);
      acc = __builtin_amdgcn_mfma_f32_16x16x32_bf16(ah, bh, acc, 0, 0, 0);
      acc = __builtin_amdgcn_mfma_f32_16x16x32_bf16(ah, bl, acc, 0, 0, 0);
      acc = __builtin_amdgcn_mfma_f32_16x16x32_bf16(al, bh, acc, 0, 0, 0);
    }

    // D frag: row = (lane>>4)*4 + r, col = lane&15  [m89-verified layout]
#pragma unroll
    for (int r = 0; r < 4; ++r) {
      int grow = r0 + (lane >> 4) * 4 + r;
      gateS[grow * GST + colA] = acc[r];
    }
    __syncthreads();

    // --- LSTM cell: one (b,u) pair per thread, c in register ---
    const float* gb = &gateS[ab * GST];
    float gi = gb[au]          + biasS[au];
    float gg = gb[4 + au]      + biasS[4 + au];
    float gf = gb[8 + au]      + biasS[8 + au];
    float go = gb[12 + au]     + biasS[12 + au];
    float iv = sigm(gi);
    float gv = tanhf(gg);
    float fv = sigm(gf + 1.0f);        // Haiku forget bias +1
    float ov = sigm(go);
    float cn = fv * c_ + iv * gv;
    float hn = ov * tanhf(cn);
    out[((size_t)t * BATCH + ab) * HID + unit] = hn;

    // fold next step's reset mask into stored h and register c
    float keep = 1.0f;
    if (t + 1 < TSTEPS) keep = 1.0f - (float)rst[(t + 1) * BATCH + ab];
    c_ = cn * keep;
    float hk = hn * keep;
    unsigned short hh = f2bf(hk);
    hbhi[wb + ab * HID + unit] = hh;
    hblo[wb + ab * HID + unit] = f2bf(hk - bf2f(hh));

    __threadfence();                   // device-scope release of h writes
    grid.sync();                       // all WGs see fresh h for step t+1
  }
}

extern "C" void kernel_launch(void* const* d_in, const int* in_sizes, int n_in,
                              void* d_out, int out_size, void* d_ws, size_t ws_size,
                              hipStream_t stream) {
  const float* x   = (const float*)d_in[0];
  const int*   rst = (const int*)d_in[1];
  const float* W   = (const float*)d_in[2];
  const float* b   = (const float*)d_in[3];
  float* out = (float*)d_out;

  // ws layout: x_hi | x_lo | h_hi(double-buffered) | h_lo(double-buffered)
  unsigned short* xhi  = (unsigned short*)d_ws;
  unsigned short* xlo  = xhi + (size_t)TSTEPS * BATCH * DIN;
  unsigned short* hbhi = xlo + (size_t)TSTEPS * BATCH * DIN;
  unsigned short* hblo = hbhi + 2 * BATCH * HID;

  int n4 = TSTEPS * BATCH * DIN / 4;
  hipLaunchKernelGGL(split_x_kernel, dim3(n4 / 256), dim3(256), 0, stream,
                     x, xhi, xlo, n4);

  void* args[] = {(void*)&xhi, (void*)&xlo, (void*)&rst, (void*)&W, (void*)&b,
                  (void*)&out, (void*)&hbhi, (void*)&hblo};
  hipLaunchCooperativeKernel((void*)lstm_persistent, dim3(NWG), dim3(NTHR),
                             args, 0, stream);
}

// Round 4
// 7058.774 us; speedup vs baseline: 2.9833x; 2.9833x over previous
//
#include <hip/hip_runtime.h>
#include <hip/hip_cooperative_groups.h>

namespace cg = cooperative_groups;

#define TSTEPS 512
#define BATCH  64
#define DIN    256
#define HID    512
#define G4H    2048
#define NWG    128
#define UPW    4            // hidden units per workgroup (NWG*UPW == HID)
#define NTHR   256
#define KTOT   768          // D + H
#define WST    776          // Wt LDS row stride in bf16 elems (R1-proven)
#define GST    17           // gate staging stride (floats)

typedef __attribute__((ext_vector_type(8))) short bf16x8;
typedef __attribute__((ext_vector_type(4))) float f32x4;

#define MFMA(A,B,C) __builtin_amdgcn_mfma_f32_16x16x32_bf16(A,B,C,0,0,0)

__device__ __forceinline__ unsigned short f2bf(float f) {
  unsigned u = __float_as_uint(f);
  u += 0x7fffu + ((u >> 16) & 1u);   // RNE truncate to bf16
  return (unsigned short)(u >> 16);
}
__device__ __forceinline__ float bf2f(unsigned short s) {
  return __uint_as_float((unsigned)s << 16);
}
__device__ __forceinline__ float sigm(float x) { return 1.0f / (1.0f + __expf(-x)); }

// One-time: split x (fp32) into hi/lo bf16 planes (R1-proven).
__global__ void split_x_kernel(const float* __restrict__ x,
                               unsigned short* __restrict__ xhi,
                               unsigned short* __restrict__ xlo, int n4) {
  int i = blockIdx.x * blockDim.x + threadIdx.x;
  if (i >= n4) return;
  float4 v = reinterpret_cast<const float4*>(x)[i];
  unsigned short h0 = f2bf(v.x), h1 = f2bf(v.y), h2 = f2bf(v.z), h3 = f2bf(v.w);
  ushort4 hi = make_ushort4(h0, h1, h2, h3);
  ushort4 lo = make_ushort4(f2bf(v.x - bf2f(h0)), f2bf(v.y - bf2f(h1)),
                            f2bf(v.z - bf2f(h2)), f2bf(v.w - bf2f(h3)));
  reinterpret_cast<ushort4*>(xhi)[i] = hi;
  reinterpret_cast<ushort4*>(xlo)[i] = lo;
}

// R1 kernel body; sync replaced by atomic-counter barrier + agent-atomic h exchange.
__global__ void __launch_bounds__(NTHR, 1)
lstm_persistent(const unsigned short* __restrict__ xhi,
                const unsigned short* __restrict__ xlo,
                const int* __restrict__ rst,
                const float* __restrict__ W,
                const float* __restrict__ bias,
                float* __restrict__ out,
                unsigned short* __restrict__ hbhi,
                unsigned short* __restrict__ hblo,
                unsigned* __restrict__ cnt) {
  __shared__ unsigned short WtHi[16 * WST];
  __shared__ unsigned short WtLo[16 * WST];
  __shared__ float gateS[BATCH * GST];
  __shared__ float biasS[16];

  const int tid = threadIdx.x;
  const int wg  = blockIdx.x;
  const int j0  = wg * UPW;

  // --- prologue: W slice -> LDS (transposed, hi/lo), bias (R1 verbatim) ---
  for (int flat = tid; flat < KTOT * 16; flat += NTHR) {
    int k = flat >> 4;
    int c = flat & 15;                        // LDS col: sec*4 + u
    int gcol = (c >> 2) * HID + j0 + (c & 3); // i|g|f|o sections of 4H
    float w = W[(size_t)k * G4H + gcol];
    unsigned short h = f2bf(w);
    WtHi[c * WST + k] = h;
    WtLo[c * WST + k] = f2bf(w - bf2f(h));
  }
  if (tid < 16) biasS[tid] = bias[(tid >> 2) * HID + j0 + (tid & 3)];
  __syncthreads();
  // one-time grid sync: keeps the kernel cg-using (proven R1 launch config)
  cg::grid_group grid = cg::this_grid();
  grid.sync();

  // --- per-thread geometry (R1 verbatim) ---
  const int lane = tid & 63;
  const int wave = tid >> 6;
  const int r0   = wave * 16;            // this wave's 16 batch rows
  const int arow = r0 + (lane & 15);     // A row (batch index)
  const int klo  = (lane >> 4) * 8;      // per-lane K base within K=32 chunk
  const int colA = lane & 15;            // output column within tile

  const unsigned short* bh_ = &WtHi[colA * WST + klo];
  const unsigned short* bl_ = &WtLo[colA * WST + klo];

  const unsigned long long* hb64h = reinterpret_cast<const unsigned long long*>(hbhi);
  const unsigned long long* hb64l = reinterpret_cast<const unsigned long long*>(hblo);
  unsigned long long* wb64h = reinterpret_cast<unsigned long long*>(hbhi);
  unsigned long long* wb64l = reinterpret_cast<unsigned long long*>(hblo);

  float cReg[4] = {0.f, 0.f, 0.f, 0.f};   // wave-0 cell state (4 units)

  for (int t = 0; t < TSTEPS; ++t) {
    f32x4 acc = {0.f, 0.f, 0.f, 0.f};
    const unsigned short* xrh = xhi + ((size_t)t * BATCH + arow) * DIN + klo;
    const unsigned short* xrl = xlo + ((size_t)t * BATCH + arow) * DIN + klo;

    // K = 0..255 from x_t  (3-product bf16 split, R1 verbatim)
#pragma unroll
    for (int kk = 0; kk < DIN / 32; ++kk) {
      int kb = kk * 32;
      bf16x8 ah = *reinterpret_cast<const bf16x8*>(xrh + kb);
      bf16x8 al = *reinterpret_cast<const bf16x8*>(xrl + kb);
      bf16x8 bh = *reinterpret_cast<const bf16x8*>(bh_ + kb);
      bf16x8 bl = *reinterpret_cast<const bf16x8*>(bl_ + kb);
      acc = MFMA(ah, bh, acc); acc = MFMA(ah, bl, acc); acc = MFMA(al, bh, acc);
    }
    // K = 256..767 from h (skip at t=0: h0 == 0)
    if (t) {
      const int rbase = (t & 1) * 8192 + arow * 128 + (klo >> 2);  // u64 units
#pragma unroll
      for (int kk = 0; kk < HID / 32; ++kk) {
        union { unsigned long long q[2]; bf16x8 v; } uh, ul;
        uh.q[0] = __hip_atomic_load(const_cast<unsigned long long*>(hb64h + rbase + kk*8),
                                    __ATOMIC_RELAXED, __HIP_MEMORY_SCOPE_AGENT);
        uh.q[1] = __hip_atomic_load(const_cast<unsigned long long*>(hb64h + rbase + kk*8 + 1),
                                    __ATOMIC_RELAXED, __HIP_MEMORY_SCOPE_AGENT);
        ul.q[0] = __hip_atomic_load(const_cast<unsigned long long*>(hb64l + rbase + kk*8),
                                    __ATOMIC_RELAXED, __HIP_MEMORY_SCOPE_AGENT);
        ul.q[1] = __hip_atomic_load(const_cast<unsigned long long*>(hb64l + rbase + kk*8 + 1),
                                    __ATOMIC_RELAXED, __HIP_MEMORY_SCOPE_AGENT);
        int kb = kk * 32;
        bf16x8 bh = *reinterpret_cast<const bf16x8*>(bh_ + DIN + kb);
        bf16x8 bl = *reinterpret_cast<const bf16x8*>(bl_ + DIN + kb);
        acc = MFMA(uh.v, bh, acc); acc = MFMA(uh.v, bl, acc); acc = MFMA(ul.v, bh, acc);
      }
    }

    // stage gates (D layout: row=(lane>>4)*4+r, col=lane&15 — m89-verified)
#pragma unroll
    for (int r = 0; r < 4; ++r) {
      int grow = r0 + (lane >> 4) * 4 + r;
      gateS[grow * GST + colA] = acc[r];
    }
    __syncthreads();

    // --- cell phase: wave 0, one batch row per lane, 4 units each ---
    if (tid < BATCH) {
      const int b_ = tid;
      float keep = 1.0f;
      if (t + 1 < TSTEPS) keep = 1.0f - (float)rst[(t + 1) * BATCH + b_];
      const float* g = &gateS[b_ * GST];
      float hv[4];
      unsigned short vh[4], vl[4];
#pragma unroll
      for (int uu = 0; uu < 4; ++uu) {
        float gi = g[uu]      + biasS[uu];
        float gg = g[4 + uu]  + biasS[4 + uu];
        float gf = g[8 + uu]  + biasS[8 + uu] + 1.0f;   // Haiku forget bias
        float go = g[12 + uu] + biasS[12 + uu];
        float iv = sigm(gi), gv = tanhf(gg), fv = sigm(gf), ov = sigm(go);
        float cn = fv * cReg[uu] + iv * gv;
        float hn = ov * tanhf(cn);
        hv[uu] = hn;
        cReg[uu] = cn * keep;
        float hk = hn * keep;
        unsigned short hh_ = f2bf(hk);
        vh[uu] = hh_;
        vl[uu] = f2bf(hk - bf2f(hh_));
      }
      f32x4 o = {hv[0], hv[1], hv[2], hv[3]};
      *reinterpret_cast<f32x4*>(out + ((size_t)t * BATCH + b_) * HID + j0) = o;
      if (t + 1 < TSTEPS) {
        unsigned long long qh = (unsigned long long)vh[0] | ((unsigned long long)vh[1] << 16)
                              | ((unsigned long long)vh[2] << 32) | ((unsigned long long)vh[3] << 48);
        unsigned long long ql = (unsigned long long)vl[0] | ((unsigned long long)vl[1] << 16)
                              | ((unsigned long long)vl[2] << 32) | ((unsigned long long)vl[3] << 48);
        size_t ho = (size_t)((t + 1) & 1) * 8192 + (size_t)b_ * 128 + wg;
        __hip_atomic_store(wb64h + ho, qh, __ATOMIC_RELAXED, __HIP_MEMORY_SCOPE_AGENT);
        __hip_atomic_store(wb64l + ho, ql, __ATOMIC_RELAXED, __HIP_MEMORY_SCOPE_AGENT);
      }
    }

    // --- barrier: drain (syncthreads waits vmcnt) -> arrive -> spin -> release ---
    __syncthreads();
    if (t + 1 < TSTEPS) {
      if (tid == 0) {
        __hip_atomic_fetch_add(cnt, 1u, __ATOMIC_RELAXED, __HIP_MEMORY_SCOPE_AGENT);
        const unsigned tgt = (unsigned)(t + 1) * NWG;
        while (__hip_atomic_load(cnt, __ATOMIC_RELAXED, __HIP_MEMORY_SCOPE_AGENT) < tgt)
          __builtin_amdgcn_s_sleep(1);
      }
      __syncthreads();
      asm volatile("" ::: "memory");
    }
  }
}

extern "C" void kernel_launch(void* const* d_in, const int* in_sizes, int n_in,
                              void* d_out, int out_size, void* d_ws, size_t ws_size,
                              hipStream_t stream) {
  const float* x   = (const float*)d_in[0];
  const int*   rst = (const int*)d_in[1];
  const float* W   = (const float*)d_in[2];
  const float* b   = (const float*)d_in[3];
  float* out = (float*)d_out;
  char* ws = (char*)d_ws;

  // ws layout (bytes): cnt(256) | hbhi(128K) | hblo(128K) | xhi(16M) | xlo(16M)
  unsigned*       cnt  = (unsigned*)(ws + 0);
  unsigned short* hbhi = (unsigned short*)(ws + 256);
  unsigned short* hblo = (unsigned short*)(ws + 256 + 131072);
  unsigned short* xhi  = (unsigned short*)(ws + 262400);
  unsigned short* xlo  = (unsigned short*)(ws + 262400 + 16777216);

  hipMemsetAsync(ws, 0, 256, stream);   // barrier counter only (h needs no init)

  int n4 = TSTEPS * BATCH * DIN / 4;
  hipLaunchKernelGGL(split_x_kernel, dim3(n4 / 256), dim3(256), 0, stream,
                     x, xhi, xlo, n4);

  void* args[] = {(void*)&xhi, (void*)&xlo, (void*)&rst, (void*)&W, (void*)&b,
                  (void*)&out, (void*)&hbhi, (void*)&hblo, (void*)&cnt};
  hipLaunchCooperativeKernel((void*)lstm_persistent, dim3(NWG), dim3(NTHR),
                             args, 0, stream);
}

// Round 5
// 5960.155 us; speedup vs baseline: 3.5332x; 1.1843x over previous
//
#include <hip/hip_runtime.h>
#include <hip/hip_cooperative_groups.h>

namespace cg = cooperative_groups;

#define TSTEPS 512
#define BATCH  64
#define DIN    256
#define HID    512
#define G4H    2048
#define NWG    128
#define UPW    4            // hidden units per workgroup (NWG*UPW == HID)
#define NTHR   256
#define KTOT   768          // D + H
#define WST    776          // Wt LDS row stride in bf16 elems (R1/R4-proven)
#define GST    17           // gate staging stride (floats)

typedef __attribute__((ext_vector_type(8))) short bf16x8;
typedef __attribute__((ext_vector_type(4))) float f32x4;

#define MFMA(A,B,C) __builtin_amdgcn_mfma_f32_16x16x32_bf16(A,B,C,0,0,0)
#define ALDU64(p) __hip_atomic_load(const_cast<unsigned long long*>(p), __ATOMIC_RELAXED, __HIP_MEMORY_SCOPE_AGENT)

__device__ __forceinline__ unsigned short f2bf(float f) {
  unsigned u = __float_as_uint(f);
  u += 0x7fffu + ((u >> 16) & 1u);   // RNE truncate to bf16
  return (unsigned short)(u >> 16);
}
__device__ __forceinline__ float bf2f(unsigned short s) {
  return __uint_as_float((unsigned)s << 16);
}
__device__ __forceinline__ float sigm(float x) { return 1.0f / (1.0f + __expf(-x)); }

// One-time: split x (fp32) into hi/lo bf16 planes (R1/R4-proven).
__global__ void split_x_kernel(const float* __restrict__ x,
                               unsigned short* __restrict__ xhi,
                               unsigned short* __restrict__ xlo, int n4) {
  int i = blockIdx.x * blockDim.x + threadIdx.x;
  if (i >= n4) return;
  float4 v = reinterpret_cast<const float4*>(x)[i];
  unsigned short h0 = f2bf(v.x), h1 = f2bf(v.y), h2 = f2bf(v.z), h3 = f2bf(v.w);
  ushort4 hi = make_ushort4(h0, h1, h2, h3);
  ushort4 lo = make_ushort4(f2bf(v.x - bf2f(h0)), f2bf(v.y - bf2f(h1)),
                            f2bf(v.z - bf2f(h2)), f2bf(v.w - bf2f(h3)));
  reinterpret_cast<ushort4*>(xhi)[i] = hi;
  reinterpret_cast<ushort4*>(xlo)[i] = lo;
}

__global__ void __launch_bounds__(NTHR, 1)
lstm_persistent(const unsigned short* __restrict__ xhi,
                const unsigned short* __restrict__ xlo,
                const int* __restrict__ rst,
                const float* __restrict__ W,
                const float* __restrict__ bias,
                float* __restrict__ out,
                unsigned short* __restrict__ hbhi,
                unsigned short* __restrict__ hblo,
                unsigned* __restrict__ cnt) {
  __shared__ unsigned short WtHi[16 * WST];
  __shared__ unsigned short WtLo[16 * WST];
  __shared__ float gateS[BATCH * GST];
  __shared__ float biasS[16];

  const int tid = threadIdx.x;
  const int wg  = blockIdx.x;
  const int j0  = wg * UPW;

  // --- prologue: W slice -> LDS (transposed, hi/lo), bias (R4 verbatim) ---
  for (int flat = tid; flat < KTOT * 16; flat += NTHR) {
    int k = flat >> 4;
    int c = flat & 15;                        // LDS col: sec*4 + u
    int gcol = (c >> 2) * HID + j0 + (c & 3); // i|g|f|o sections of 4H
    float w = W[(size_t)k * G4H + gcol];
    unsigned short h = f2bf(w);
    WtHi[c * WST + k] = h;
    WtLo[c * WST + k] = f2bf(w - bf2f(h));
  }
  if (tid < 16) biasS[tid] = bias[(tid >> 2) * HID + j0 + (tid & 3)];
  __syncthreads();
  cg::grid_group grid = cg::this_grid();
  grid.sync();

  // --- per-thread geometry (R4 verbatim) ---
  const int lane = tid & 63;
  const int wave = tid >> 6;
  const int r0   = wave * 16;            // this wave's 16 batch rows
  const int arow = r0 + (lane & 15);     // A row (batch index)
  const int klo  = (lane >> 4) * 8;      // per-lane K base within K=32 chunk
  const int colA = lane & 15;            // output column within tile

  const unsigned short* bh_ = &WtHi[colA * WST + klo];
  const unsigned short* bl_ = &WtLo[colA * WST + klo];

  const unsigned long long* hb64h = reinterpret_cast<const unsigned long long*>(hbhi);
  const unsigned long long* hb64l = reinterpret_cast<const unsigned long long*>(hblo);
  unsigned long long* wb64h = reinterpret_cast<unsigned long long*>(hbhi);
  unsigned long long* wb64l = reinterpret_cast<unsigned long long*>(hblo);

  // cell identity: wave `wave`, lanes 0..15 each own one batch row, 4 units
  const int crow = r0 + lane;            // valid when lane < 16
  float cReg[4] = {0.f, 0.f, 0.f, 0.f};

  // x-part GEMM for step TT (A from pre-split planes, B from LDS) -> single chain
#define XPART(TT, A0) do {                                                      \
    const unsigned short* xrh_ = xhi + ((size_t)(TT) * BATCH + arow) * DIN + klo; \
    const unsigned short* xrl_ = xlo + ((size_t)(TT) * BATCH + arow) * DIN + klo; \
    _Pragma("unroll")                                                           \
    for (int kk = 0; kk < DIN / 32; ++kk) {                                     \
      int kb = kk * 32;                                                         \
      bf16x8 ah = *reinterpret_cast<const bf16x8*>(xrh_ + kb);                  \
      bf16x8 al = *reinterpret_cast<const bf16x8*>(xrl_ + kb);                  \
      bf16x8 bh = *reinterpret_cast<const bf16x8*>(bh_ + kb);                   \
      bf16x8 bl = *reinterpret_cast<const bf16x8*>(bl_ + kb);                   \
      A0 = MFMA(ah, bh, A0); A0 = MFMA(ah, bl, A0); A0 = MFMA(al, bh, A0);      \
    }                                                                           \
  } while (0)

  f32x4 accx = {0.f, 0.f, 0.f, 0.f};
  XPART(0, accx);

  for (int t = 0; t < TSTEPS; ++t) {
    // rst prefetch (consumed in cell phase; overlaps h loads + MFMAs)
    int rstv = 0;
    if (lane < 16 && t + 1 < TSTEPS) rstv = rst[(t + 1) * BATCH + crow];

    f32x4 accA = accx, accB = {0.f, 0.f, 0.f, 0.f};

    if (t) {
      const int rbase = (t & 1) * 8192 + arow * 128 + (klo >> 2);  // u64 units
      // ---- issue ALL 64 h loads first: one coherent-point round trip ----
      unsigned long long qh[32], ql[32];
#pragma unroll
      for (int J = 0; J < 16; ++J) {
        qh[2*J]   = ALDU64(hb64h + rbase + J*8);
        qh[2*J+1] = ALDU64(hb64h + rbase + J*8 + 1);
        ql[2*J]   = ALDU64(hb64l + rbase + J*8);
        ql[2*J+1] = ALDU64(hb64l + rbase + J*8 + 1);
      }
      // ---- consume: 2 accumulator chains halve dependent-MFMA latency ----
#pragma unroll
      for (int J = 0; J < 16; ++J) {
        union { unsigned long long q[2]; bf16x8 v; } uh, ul;
        uh.q[0] = qh[2*J]; uh.q[1] = qh[2*J+1];
        ul.q[0] = ql[2*J]; ul.q[1] = ql[2*J+1];
        int kb = J * 32;
        bf16x8 bh = *reinterpret_cast<const bf16x8*>(bh_ + DIN + kb);
        bf16x8 bl = *reinterpret_cast<const bf16x8*>(bl_ + DIN + kb);
        if (J < 8) {
          accA = MFMA(uh.v, bh, accA); accA = MFMA(uh.v, bl, accA); accA = MFMA(ul.v, bh, accA);
        } else {
          accB = MFMA(uh.v, bh, accB); accB = MFMA(uh.v, bl, accB); accB = MFMA(ul.v, bh, accB);
        }
      }
    }

    // stage gates (D layout: row=(lane>>4)*4+r, col=lane&15 — m89-verified)
#pragma unroll
    for (int r = 0; r < 4; ++r) {
      int grow = r0 + (lane >> 4) * 4 + r;
      gateS[grow * GST + colA] = accA[r] + accB[r];
    }
    __syncthreads();

    // --- cell phase: all 4 waves, lanes 0..15, one batch row each ---
    if (lane < 16) {
      const float keep = 1.0f - (float)rstv;
      const float* g = &gateS[crow * GST];
      float hv[4];
      unsigned short vh[4], vl[4];
#pragma unroll
      for (int uu = 0; uu < 4; ++uu) {
        float gi = g[uu]      + biasS[uu];
        float gg = g[4 + uu]  + biasS[4 + uu];
        float gf = g[8 + uu]  + biasS[8 + uu] + 1.0f;   // Haiku forget bias
        float go = g[12 + uu] + biasS[12 + uu];
        float iv = sigm(gi), gv = tanhf(gg), fv = sigm(gf), ov = sigm(go);
        float cn = fv * cReg[uu] + iv * gv;
        float hn = ov * tanhf(cn);
        hv[uu] = hn;
        cReg[uu] = cn * keep;
        float hk = hn * keep;
        unsigned short hh_ = f2bf(hk);
        vh[uu] = hh_;
        vl[uu] = f2bf(hk - bf2f(hh_));
      }
      f32x4 o = {hv[0], hv[1], hv[2], hv[3]};
      *reinterpret_cast<f32x4*>(out + ((size_t)t * BATCH + crow) * HID + j0) = o;
      if (t + 1 < TSTEPS) {
        unsigned long long qh = (unsigned long long)vh[0] | ((unsigned long long)vh[1] << 16)
                              | ((unsigned long long)vh[2] << 32) | ((unsigned long long)vh[3] << 48);
        unsigned long long ql = (unsigned long long)vl[0] | ((unsigned long long)vl[1] << 16)
                              | ((unsigned long long)vl[2] << 32) | ((unsigned long long)vl[3] << 48);
        size_t ho = (size_t)((t + 1) & 1) * 8192 + (size_t)crow * 128 + wg;
        __hip_atomic_store(wb64h + ho, qh, __ATOMIC_RELAXED, __HIP_MEMORY_SCOPE_AGENT);
        __hip_atomic_store(wb64l + ho, ql, __ATOMIC_RELAXED, __HIP_MEMORY_SCOPE_AGENT);
      }
    }

    // --- barrier: drain (syncthreads waits vmcnt) -> arrive -> spin -> release ---
    // next step's x-part runs UNDER the spin (independent of h)
    __syncthreads();
    if (t + 1 < TSTEPS) {
      if (tid == 0)
        __hip_atomic_fetch_add(cnt, 1u, __ATOMIC_RELAXED, __HIP_MEMORY_SCOPE_AGENT);
      accx = (f32x4){0.f, 0.f, 0.f, 0.f};
      XPART(t + 1, accx);
      if (tid == 0) {
        const unsigned tgt = (unsigned)(t + 1) * NWG;
        while (__hip_atomic_load(cnt, __ATOMIC_RELAXED, __HIP_MEMORY_SCOPE_AGENT) < tgt)
          __builtin_amdgcn_s_sleep(1);
      }
      __syncthreads();
      asm volatile("" ::: "memory");
    }
  }
#undef XPART
}

extern "C" void kernel_launch(void* const* d_in, const int* in_sizes, int n_in,
                              void* d_out, int out_size, void* d_ws, size_t ws_size,
                              hipStream_t stream) {
  const float* x   = (const float*)d_in[0];
  const int*   rst = (const int*)d_in[1];
  const float* W   = (const float*)d_in[2];
  const float* b   = (const float*)d_in[3];
  float* out = (float*)d_out;
  char* ws = (char*)d_ws;

  // ws layout (bytes): cnt(256) | hbhi(128K) | hblo(128K) | xhi(16M) | xlo(16M)
  unsigned*       cnt  = (unsigned*)(ws + 0);
  unsigned short* hbhi = (unsigned short*)(ws + 256);
  unsigned short* hblo = (unsigned short*)(ws + 256 + 131072);
  unsigned short* xhi  = (unsigned short*)(ws + 262400);
  unsigned short* xlo  = (unsigned short*)(ws + 262400 + 16777216);

  hipMemsetAsync(ws, 0, 256, stream);   // barrier counter only (h needs no init)

  int n4 = TSTEPS * BATCH * DIN / 4;
  hipLaunchKernelGGL(split_x_kernel, dim3(n4 / 256), dim3(256), 0, stream,
                     x, xhi, xlo, n4);

  void* args[] = {(void*)&xhi, (void*)&xlo, (void*)&rst, (void*)&W, (void*)&b,
                  (void*)&out, (void*)&hbhi, (void*)&hblo, (void*)&cnt};
  hipLaunchCooperativeKernel((void*)lstm_persistent, dim3(NWG), dim3(NTHR),
                             args, 0, stream);
}

// Round 6
// 4121.776 us; speedup vs baseline: 5.1090x; 1.4460x over previous
//
#include <hip/hip_runtime.h>
#include <hip/hip_cooperative_groups.h>

namespace cg = cooperative_groups;

#define TSTEPS 512
#define BATCH  64
#define DIN    256
#define HID    512
#define G4H    2048
#define NWG    128
#define UPW    4            // hidden units per workgroup (NWG*UPW == HID)
#define NTHR   256
#define KTOT   768          // D + H
#define WST    776          // Wt LDS row stride in bf16 elems (R1/R4/R5-proven)
#define GST    17           // gate staging stride (floats)

typedef __attribute__((ext_vector_type(8))) short bf16x8;
typedef __attribute__((ext_vector_type(4))) float f32x4;

#define MFMA(A,B,C) __builtin_amdgcn_mfma_f32_16x16x32_bf16(A,B,C,0,0,0)
#define ALDU64(p) __hip_atomic_load(const_cast<unsigned long long*>(p), __ATOMIC_RELAXED, __HIP_MEMORY_SCOPE_AGENT)
#define ALDU32(p) __hip_atomic_load(const_cast<unsigned*>(p), __ATOMIC_RELAXED, __HIP_MEMORY_SCOPE_AGENT)
#define ASTU64(p,v) __hip_atomic_store((p), (v), __ATOMIC_RELAXED, __HIP_MEMORY_SCOPE_AGENT)
#define ASTU32(p,v) __hip_atomic_store((p), (v), __ATOMIC_RELAXED, __HIP_MEMORY_SCOPE_AGENT)

__device__ __forceinline__ unsigned short f2bf(float f) {
  unsigned u = __float_as_uint(f);
  u += 0x7fffu + ((u >> 16) & 1u);   // RNE truncate to bf16
  return (unsigned short)(u >> 16);
}
__device__ __forceinline__ float bf2f(unsigned short s) {
  return __uint_as_float((unsigned)s << 16);
}
__device__ __forceinline__ float sigm(float x) { return 1.0f / (1.0f + __expf(-x)); }

// One-time: split x (fp32) into hi/lo bf16 planes (proven).
__global__ void split_x_kernel(const float* __restrict__ x,
                               unsigned short* __restrict__ xhi,
                               unsigned short* __restrict__ xlo, int n4) {
  int i = blockIdx.x * blockDim.x + threadIdx.x;
  if (i >= n4) return;
  float4 v = reinterpret_cast<const float4*>(x)[i];
  unsigned short h0 = f2bf(v.x), h1 = f2bf(v.y), h2 = f2bf(v.z), h3 = f2bf(v.w);
  ushort4 hi = make_ushort4(h0, h1, h2, h3);
  ushort4 lo = make_ushort4(f2bf(v.x - bf2f(h0)), f2bf(v.y - bf2f(h1)),
                            f2bf(v.z - bf2f(h2)), f2bf(v.w - bf2f(h3)));
  reinterpret_cast<ushort4*>(xhi)[i] = hi;
  reinterpret_cast<ushort4*>(xlo)[i] = lo;
}

__global__ void __launch_bounds__(NTHR, 1)
lstm_persistent(const unsigned short* __restrict__ xhi,
                const unsigned short* __restrict__ xlo,
                const int* __restrict__ rst,
                const float* __restrict__ W,
                const float* __restrict__ bias,
                float* __restrict__ out,
                unsigned long long* __restrict__ hb,      // [2][BATCH][128] u64 (bf16x4)
                unsigned* __restrict__ flags) {           // [NWG] stride 16 u32 (64B)
  __shared__ unsigned short WtHi[16 * WST];
  __shared__ unsigned short WtLo[16 * WST];
  __shared__ float gateS[BATCH * GST];
  __shared__ float biasS[16];

  const int tid = threadIdx.x;
  const int wg  = blockIdx.x;
  const int j0  = wg * UPW;

  // --- prologue: W slice -> LDS (transposed, hi/lo), bias (proven) ---
  for (int flat = tid; flat < KTOT * 16; flat += NTHR) {
    int k = flat >> 4;
    int c = flat & 15;                        // LDS col: sec*4 + u
    int gcol = (c >> 2) * HID + j0 + (c & 3); // i|g|f|o sections of 4H
    float w = W[(size_t)k * G4H + gcol];
    unsigned short h = f2bf(w);
    WtHi[c * WST + k] = h;
    WtLo[c * WST + k] = f2bf(w - bf2f(h));
  }
  if (tid < 16) biasS[tid] = bias[(tid >> 2) * HID + j0 + (tid & 3)];
  __syncthreads();
  cg::grid_group grid = cg::this_grid();
  grid.sync();                              // once; keeps proven launch config

  // --- per-thread geometry (proven) ---
  const int lane = tid & 63;
  const int wave = tid >> 6;
  const int r0   = wave * 16;
  const int arow = r0 + (lane & 15);
  const int klo  = (lane >> 4) * 8;
  const int colA = lane & 15;

  const unsigned short* bh_ = &WtHi[colA * WST + klo];
  const unsigned short* bl_ = &WtLo[colA * WST + klo];

  const int crow = r0 + lane;               // cell row (valid when lane < 16)
  float cReg[4] = {0.f, 0.f, 0.f, 0.f};

#define XPART(TT, A0) do {                                                      \
    const unsigned short* xrh_ = xhi + ((size_t)(TT) * BATCH + arow) * DIN + klo; \
    const unsigned short* xrl_ = xlo + ((size_t)(TT) * BATCH + arow) * DIN + klo; \
    _Pragma("unroll")                                                           \
    for (int kk = 0; kk < DIN / 32; ++kk) {                                     \
      int kb = kk * 32;                                                         \
      bf16x8 ah = *reinterpret_cast<const bf16x8*>(xrh_ + kb);                  \
      bf16x8 al = *reinterpret_cast<const bf16x8*>(xrl_ + kb);                  \
      bf16x8 bh = *reinterpret_cast<const bf16x8*>(bh_ + kb);                   \
      bf16x8 bl = *reinterpret_cast<const bf16x8*>(bl_ + kb);                   \
      A0 = MFMA(ah, bh, A0); A0 = MFMA(ah, bl, A0); A0 = MFMA(al, bh, A0);      \
    }                                                                           \
  } while (0)

  f32x4 accx = {0.f, 0.f, 0.f, 0.f};
  XPART(0, accx);
  int rstv = (lane < 16 && TSTEPS > 1) ? rst[1 * BATCH + crow] : 0;
  f32x4 oStash = {0.f, 0.f, 0.f, 0.f};

  for (int t = 0; t < TSTEPS; ++t) {
    f32x4 accA = accx, accB = {0.f, 0.f, 0.f, 0.f};

    if (t) {
      const int rbase = (t & 1) * 8192 + arow * 128 + (klo >> 2);  // u64 units
      // issue ALL 32 h loads; memory clobber pins them before the consume loop
      unsigned long long q[32];
#pragma unroll
      for (int J = 0; J < 16; ++J) {
        q[2*J]   = ALDU64(hb + rbase + J*8);
        q[2*J+1] = ALDU64(hb + rbase + J*8 + 1);
      }
      asm volatile("" ::: "memory");        // forbid sinking loads into consume
#pragma unroll
      for (int J = 0; J < 16; ++J) {
        union { unsigned long long qq[2]; bf16x8 v; } ua;
        ua.qq[0] = q[2*J]; ua.qq[1] = q[2*J+1];
        int kb = J * 32;
        bf16x8 bh = *reinterpret_cast<const bf16x8*>(bh_ + DIN + kb);
        bf16x8 bl = *reinterpret_cast<const bf16x8*>(bl_ + DIN + kb);
        if (J < 8) { accA = MFMA(ua.v, bh, accA); accA = MFMA(ua.v, bl, accA); }
        else       { accB = MFMA(ua.v, bh, accB); accB = MFMA(ua.v, bl, accB); }
      }
    }

    // stage gates — strictly intra-wave (wave w writes/reads rows 16w..16w+15)
#pragma unroll
    for (int r = 0; r < 4; ++r) {
      int grow = r0 + (lane >> 4) * 4 + r;
      gateS[grow * GST + colA] = accA[r] + accB[r];
    }

    // --- cell phase: lanes 0..15 of every wave, one batch row each ---
    if (lane < 16) {
      const float keep = 1.0f - (float)rstv;
      const float* g = &gateS[crow * GST];
      float hv[4];
      unsigned short vh[4];
#pragma unroll
      for (int uu = 0; uu < 4; ++uu) {
        float gi = g[uu]      + biasS[uu];
        float gg = g[4 + uu]  + biasS[4 + uu];
        float gf = g[8 + uu]  + biasS[8 + uu] + 1.0f;   // Haiku forget bias
        float go = g[12 + uu] + biasS[12 + uu];
        float iv = sigm(gi), gv = tanhf(gg), fv = sigm(gf), ov = sigm(go);
        float cn = fv * cReg[uu] + iv * gv;
        float hn = ov * tanhf(cn);
        hv[uu] = hn;
        cReg[uu] = cn * keep;
        float hk = hn * keep;
        vh[uu] = f2bf(hk);
      }
      oStash = (f32x4){hv[0], hv[1], hv[2], hv[3]};
      if (t + 1 < TSTEPS) {
        unsigned long long qh = (unsigned long long)vh[0] | ((unsigned long long)vh[1] << 16)
                              | ((unsigned long long)vh[2] << 32) | ((unsigned long long)vh[3] << 48);
        ASTU64(hb + (size_t)((t + 1) & 1) * 8192 + (size_t)crow * 128 + wg, qh);
      }
    }

    // drain h-stores (syncthreads emits vmcnt(0)) then arrive
    __syncthreads();
    if (t + 1 < TSTEPS) {
      if (tid == 0) ASTU32(flags + wg * 16, (unsigned)(t + 1));   // arrive: plain store
      // tail work rides under other WGs' arrivals + our poll
      if (lane < 16)
        *reinterpret_cast<f32x4*>(out + ((size_t)t * BATCH + crow) * HID + j0) = oStash;
      accx = (f32x4){0.f, 0.f, 0.f, 0.f};
      XPART(t + 1, accx);
      rstv = (lane < 16 && t + 2 < TSTEPS) ? rst[(t + 2) * BATCH + crow] : 0;
      if (tid < NWG) {                       // parallel detect: 1 flag per thread
        const unsigned tgt = (unsigned)(t + 1);
        while (ALDU32(flags + tid * 16) < tgt) __builtin_amdgcn_s_sleep(1);
      }
      __syncthreads();
      asm volatile("" ::: "memory");         // no hoisting h loads above release
    } else {
      if (lane < 16)
        *reinterpret_cast<f32x4*>(out + ((size_t)t * BATCH + crow) * HID + j0) = oStash;
    }
  }
#undef XPART
}

extern "C" void kernel_launch(void* const* d_in, const int* in_sizes, int n_in,
                              void* d_out, int out_size, void* d_ws, size_t ws_size,
                              hipStream_t stream) {
  const float* x   = (const float*)d_in[0];
  const int*   rst = (const int*)d_in[1];
  const float* W   = (const float*)d_in[2];
  const float* b   = (const float*)d_in[3];
  float* out = (float*)d_out;
  char* ws = (char*)d_ws;

  // ws layout (bytes): flags(8K) | hb(128K) | xhi(16M) | xlo(16M)
  unsigned*           flags = (unsigned*)(ws + 0);
  unsigned long long* hb    = (unsigned long long*)(ws + 8192);
  unsigned short*     xhi   = (unsigned short*)(ws + 8192 + 131072);
  unsigned short*     xlo   = (unsigned short*)(ws + 8192 + 131072 + 16777216);

  hipMemsetAsync(ws, 0, 8192, stream);   // flags only (h needs no init; t=0 skips h)

  int n4 = TSTEPS * BATCH * DIN / 4;
  hipLaunchKernelGGL(split_x_kernel, dim3(n4 / 256), dim3(256), 0, stream,
                     x, xhi, xlo, n4);

  void* args[] = {(void*)&xhi, (void*)&xlo, (void*)&rst, (void*)&W, (void*)&b,
                  (void*)&out, (void*)&hb, (void*)&flags};
  hipLaunchCooperativeKernel((void*)lstm_persistent, dim3(NWG), dim3(NTHR),
                             args, 0, stream);
}